// Round 6
// baseline (536.747 us; speedup 1.0000x reference)
//
#include <hip/hip_runtime.h>

// ---------------------------------------------------------------------------
// FastSelfAttention on MI355X (gfx950), round 6.
// B=8, S=4096, D=1024, H=16, DH=64.
// R6: GEMM phases software-pipelined one phase ahead: each phase waits the
// operands issued in the PREVIOUS phase, issues its MFMAs (non-blocking),
// then issues the NEXT phase's ds_reads -> LDS pipe serves reads while the
// matrix pipe drains. 4 barriers/K-tile, vmcnt(0) only when provably free.
// ---------------------------------------------------------------------------

typedef unsigned short u16;
typedef float f32x4 __attribute__((ext_vector_type(4)));
typedef short bf16x8 __attribute__((ext_vector_type(8)));

#define DEV __device__ __forceinline__

DEV u16 f2bf(float f) {
  union { float f; unsigned u; } c; c.f = f;
  return (u16)((c.u + 0x7FFFu + ((c.u >> 16) & 1u)) >> 16);
}
DEV float bf2f(u16 h) {
  union { unsigned u; float f; } c; c.u = ((unsigned)h) << 16;
  return c.f;
}

#define SBAR_  __builtin_amdgcn_s_barrier()
#define SB0_   __builtin_amdgcn_sched_barrier(0)
// rule #18: sched_barrier(0) after inline-asm lgkmcnt(0) so MFMA can't hoist
#define LGKM0_ do { asm volatile("s_waitcnt lgkmcnt(0)" ::: "memory"); SB0_; } while (0)

// --- f32 -> bf16 bulk convert ----------------------------------------------
__global__ __launch_bounds__(256) void k_cvt(const float* __restrict__ in,
                                             u16* __restrict__ out, int n4) {
  int i = blockIdx.x * 256 + threadIdx.x;
  const int stride = gridDim.x * 256;
  for (; i < n4; i += stride) {
    float4 v = reinterpret_cast<const float4*>(in)[i];
    ushort4 o;
    o.x = f2bf(v.x); o.y = f2bf(v.y); o.z = f2bf(v.z); o.w = f2bf(v.w);
    reinterpret_cast<ushort4*>(out)[i] = o;
  }
}

// --- W (K,N) f32 -> W^T (N,K) bf16 -----------------------------------------
__global__ __launch_bounds__(256) void k_transw(const float* __restrict__ W,
                                                u16* __restrict__ Wt) {
  __shared__ float tile[32][33];
  const int bn = blockIdx.x, bk = blockIdx.y;
  const int tx = threadIdx.x & 31, ty = threadIdx.x >> 5;
#pragma unroll
  for (int j = 0; j < 4; ++j)
    tile[ty + j * 8][tx] = W[(size_t)(bk * 32 + ty + j * 8) * 1024 + bn * 32 + tx];
  __syncthreads();
#pragma unroll
  for (int j = 0; j < 4; ++j)
    Wt[(size_t)(bn * 32 + ty + j * 8) * 1024 + bk * 32 + tx] = f2bf(tile[tx][ty + j * 8]);
}

// --- Wbt[b][n][k] = bf16( Wtt[n][k] * pk[b][k] * pq[b][k] ) ----------------
__global__ __launch_bounds__(256) void k_wbt(const u16* __restrict__ Wtt,
                                             const float* __restrict__ pk,
                                             const float* __restrict__ pq,
                                             u16* __restrict__ Wbt) {
  const int i = blockIdx.x * 256 + threadIdx.x;  // 1048576 threads
  const int k0 = (i & 127) * 8;
  const int n  = (i >> 7) & 1023;
  const int b  = i >> 17;
  bf16x8 wv = *reinterpret_cast<const bf16x8*>(&Wtt[n * 1024 + k0]);
  bf16x8 o;
#pragma unroll
  for (int j = 0; j < 8; ++j) {
    const float p = pk[b * 1024 + k0 + j] * pq[b * 1024 + k0 + j];
    o[j] = (short)f2bf(bf2f((u16)wv[j]) * p);
  }
  *reinterpret_cast<bf16x8*>(&Wbt[(size_t)b * 1048576 + (size_t)n * 1024 + k0]) = o;
}

// --- 256x256 GEMM, pipelined phases, LDS-staged epilogue -------------------
// C = A(Mx1024) x Bt(Nx1024)^T. 512 threads = 8 waves (2M x 4N), BK=64,
// double-buffered 128 KiB XOR-swizzled LDS.
// Phase p: wait operands (issued phase p-1) -> MFMA quadrant -> issue next
// phase's reads -> barrier. Quadrants: Q00,Q01,Q11,Q10.
// EPI 0: bf16 out; whole block's cols land in C0 (ci<gcols/2, bias0) or C1.
// EPI 2: f32 out = acc + bias0[col] + bf2f(extra[row,col]); Bt per-batch.
template <int EPI>
__global__ __launch_bounds__(512, 2) void k_gemm8(const u16* __restrict__ A,
                                                  const u16* __restrict__ Bt,
                                                  const float* __restrict__ bias0,
                                                  const float* __restrict__ bias1,
                                                  const u16* __restrict__ extra,
                                                  float* __restrict__ Cf,
                                                  u16* __restrict__ C0,
                                                  u16* __restrict__ C1,
                                                  int gcols) {
  __shared__ __align__(16) u16 lds[2 * 32768];  // [buf][A|B][256][64]
  const int tid = threadIdx.x;
  const int w = tid >> 6, lane = tid & 63;
  const int wm = w >> 2, wn = w & 3;

  // chunked XCD swizzle (nwg % 8 == 0)
  const int nwg = gridDim.x;
  const int swz = (blockIdx.x & 7) * (nwg >> 3) + (blockIdx.x >> 3);
  const int ci = swz % gcols, ri = swz / gcols;
  const int row0 = ri * 256, col0 = ci * 256;

  // staging: dest row = half*128 + p*64 + (tid>>3), slot = tid&7; source
  // pre-swizzled so physical slot s holds logical slot s ^ (row&7).
  const int sr = tid >> 3;
  const int ls8 = ((tid & 7) ^ (sr & 7)) * 8;
  const u16* gA = A + (size_t)(row0 + sr) * 1024 + ls8;
  const u16* gB;
  if (EPI == 2) {
    gB = Bt + (size_t)(row0 >> 12) * 1048576 + (size_t)(col0 + sr) * 1024 + ls8;
  } else {
    gB = Bt + (size_t)(col0 + sr) * 1024 + ls8;
  }

  auto stage = [&](int buf, int mat, int half, int kt, const u16* g) {
#pragma unroll
    for (int p = 0; p < 2; ++p) {
      const u16* src = g + (size_t)(half * 128 + p * 64) * 1024 + kt;
      u16* dst = (u16*)&lds[buf * 32768 + mat * 16384 + half * 8192 + p * 4096 + w * 512];
      __builtin_amdgcn_global_load_lds(
          (const __attribute__((address_space(1))) void*)src,
          (__attribute__((address_space(3))) void*)dst, 16, 0, 0);
    }
  };

  f32x4 acc[8][4] = {};

  // prologue: tile 0 -> buf0, tile 1 -> buf1
#pragma unroll
  for (int tt = 0; tt < 2; ++tt) {
    stage(tt, 0, 0, tt * 64, gA);
    stage(tt, 0, 1, tt * 64, gA);
    stage(tt, 1, 0, tt * 64, gB);
    stage(tt, 1, 1, tt * 64, gB);
  }
  asm volatile("s_waitcnt vmcnt(8)" ::: "memory");  // tile0 landed
  SBAR_;
  SB0_;

  const int lr15 = lane & 15, lhi = lane >> 4, lx = lane & 7;
  bf16x8 A0[4][2], A1[4][2], B0[2][2], B1[2][2];

  // fragment read helpers (row-major [256][64] bf16, XOR-swizzled slots)
#define RD_A(dstv, bufp, ahalf)                                                \
  _Pragma("unroll") for (int mi = 0; mi < 4; ++mi)                             \
  _Pragma("unroll") for (int ks = 0; ks < 2; ++ks)                             \
    dstv[mi][ks] = *reinterpret_cast<const bf16x8*>(                           \
        &(bufp)[(wm * 128 + (ahalf) * 64 + mi * 16 + lr15) * 64 +              \
                (((ks << 2) | lhi) ^ lx) * 8]);
#define RD_B(dstv, bufp, bhalf)                                                \
  _Pragma("unroll") for (int ni = 0; ni < 2; ++ni)                             \
  _Pragma("unroll") for (int ks = 0; ks < 2; ++ks)                             \
    dstv[ni][ks] = *reinterpret_cast<const bf16x8*>(                           \
        &(bufp)[(wn * 64 + (bhalf) * 32 + ni * 16 + lr15) * 64 +               \
                (((ks << 2) | lhi) ^ lx) * 8]);
#define MFMA_Q(ar, br, mo, no)                                                 \
  _Pragma("unroll") for (int mi = 0; mi < 4; ++mi)                             \
  _Pragma("unroll") for (int ni = 0; ni < 2; ++ni)                             \
  _Pragma("unroll") for (int ks = 0; ks < 2; ++ks)                             \
    acc[(mo) + mi][(no) + ni] = __builtin_amdgcn_mfma_f32_16x16x32_bf16(       \
        ar[mi][ks], br[ni][ks], acc[(mo) + mi][(no) + ni], 0, 0, 0);

  // pre-read tile0 operands for P0
  {
    const u16* bA = &lds[0];
    const u16* bB = bA + 16384;
    RD_A(A0, bA, 0);
    RD_B(B0, bB, 0);
  }

  int cur = 0;
  for (int t = 0; t < 16; ++t) {
    const u16* bA = &lds[cur * 32768];
    const u16* bB = bA + 16384;
    const u16* nA = &lds[(cur ^ 1) * 32768];
    const u16* nB = nA + 16384;
    const int kt2 = (t + 2) * 64;

    // ---- P0: wait A0,B0; MFMA Q00; issue B1 reads ----
    LGKM0_;
    __builtin_amdgcn_s_setprio(1);
    MFMA_Q(A0, B0, 0, 0);
    __builtin_amdgcn_s_setprio(0);
    SB0_;
    RD_B(B1, bB, 1);
    SBAR_;

    // ---- P1: wait B1; MFMA Q01; issue A1 reads; free vmcnt(0) ----
    LGKM0_;
    __builtin_amdgcn_s_setprio(1);
    MFMA_Q(A0, B1, 0, 2);
    __builtin_amdgcn_s_setprio(0);
    SB0_;
    RD_A(A1, bA, 1);
    // only tile t+1's stages (issued a full tile ago) are outstanding -> free
    asm volatile("s_waitcnt vmcnt(0)" ::: "memory");
    SBAR_;
    SB0_;  // P2's next-buf reads must stay below this barrier

    // ---- P2: wait A1; MFMA Q11; issue next-tile A0' reads; stage B(t+2) ----
    LGKM0_;
    __builtin_amdgcn_s_setprio(1);
    MFMA_Q(A1, B1, 4, 2);
    __builtin_amdgcn_s_setprio(0);
    SB0_;
    if (t < 15) { RD_A(A0, nA, 0); }
    if (t < 14) { stage(cur, 1, 0, kt2, gB); stage(cur, 1, 1, kt2, gB); }
    SBAR_;
    SB0_;  // P3's stage must stay below this barrier

    // ---- P3: MFMA Q10 (operands already waited); issue B0' reads; stage A ----
    __builtin_amdgcn_s_setprio(1);
    MFMA_Q(A1, B0, 4, 0);
    __builtin_amdgcn_s_setprio(0);
    SB0_;
    if (t < 15) { RD_B(B0, nB, 0); }
    if (t < 14) { stage(cur, 0, 0, kt2, gA); stage(cur, 0, 1, kt2, gA); }
    SBAR_;
    SB0_;

    cur ^= 1;
  }
#undef RD_A
#undef RD_B
#undef MFMA_Q

  // ---- epilogue: LDS-staged coalesced stores (unchanged from R4) ----
  if constexpr (EPI == 0) {
    u16* cl = (u16*)lds;
    const bool lo = (ci < (gcols >> 1));
    const float* bias = lo ? bias0 : bias1;
    u16* dst = lo ? C0 : C1;
    const int colloc0 = col0 - (lo ? 0 : 1024);
#pragma unroll
    for (int n = 0; n < 4; ++n) {
      const int cc = wn * 64 + n * 16 + lr15;
      const float bv = bias[colloc0 + cc];
#pragma unroll
      for (int m = 0; m < 8; ++m) {
        const int rb = wm * 128 + m * 16 + lhi * 4;
#pragma unroll
        for (int j = 0; j < 4; ++j) {
          const int r = rb + j;
          cl[r * 256 + (cc ^ ((r & 12) << 2))] = f2bf(acc[m][n][j] + bv);
        }
      }
    }
    __syncthreads();
#pragma unroll
    for (int pass = 0; pass < 16; ++pass) {
      const int idx = pass * 512 + tid;
      const int r = idx >> 5, g = idx & 31;  // 256 rows x 32 groups of 8 u16
      bf16x8 v = *reinterpret_cast<const bf16x8*>(
          &cl[r * 256 + ((g * 8) ^ ((r & 12) << 2))]);
      *reinterpret_cast<bf16x8*>(
          &dst[(size_t)(row0 + r) * 1024 + colloc0 + g * 8]) = v;
    }
  } else {
    float* clf = (float*)lds;
#pragma unroll
    for (int half = 0; half < 2; ++half) {
      __syncthreads();
      if (wm == half) {
#pragma unroll
        for (int n = 0; n < 4; ++n) {
          const int cc = wn * 64 + n * 16 + lr15;
#pragma unroll
          for (int m = 0; m < 8; ++m) {
            const int rb = m * 16 + lhi * 4;
#pragma unroll
            for (int j = 0; j < 4; ++j) {
              const int r = rb + j;
              clf[r * 256 + (cc ^ ((r & 12) << 2))] = acc[m][n][j];
            }
          }
        }
      }
      __syncthreads();
#pragma unroll
      for (int pass = 0; pass < 16; ++pass) {
        const int idx = pass * 512 + tid;
        const int r = idx >> 6, g = idx & 63;  // 128 rows x 64 groups of 4 f32
        f32x4 v = *reinterpret_cast<const f32x4*>(
            &clf[r * 256 + ((g * 4) ^ ((r & 12) << 2))]);
        const int grow = row0 + half * 128 + r;
        const int gcol = col0 + g * 4;
        ushort4 e = *reinterpret_cast<const ushort4*>(
            &extra[(size_t)grow * 1024 + gcol]);
        float4 o;
        o.x = v[0] + bias0[gcol + 0] + bf2f(e.x);
        o.y = v[1] + bias0[gcol + 1] + bf2f(e.y);
        o.z = v[2] + bias0[gcol + 2] + bf2f(e.z);
        o.w = v[3] + bias0[gcol + 3] + bf2f(e.w);
        *reinterpret_cast<float4*>(&Cf[(size_t)grow * 1024 + gcol]) = o;
      }
    }
  }
}

// --- score[b,h,s] = (X[b,s,:].Weff[:,h] + bias[h])*scale + mask[b,s] -------
template <int HAS_PQ>
__global__ __launch_bounds__(256) void k_score(const u16* __restrict__ X,
                                               const float* __restrict__ Wa,
                                               const float* __restrict__ bias,
                                               const float* __restrict__ mask,
                                               const float* __restrict__ pq,
                                               float* __restrict__ score,
                                               float scale) {
  __shared__ float waT[16][1024];  // [h][d]
  const int b = blockIdx.y;
  for (int t = threadIdx.x; t < 16384; t += 256) {
    const int d = t >> 4, h = t & 15;
    float wv = Wa[t];
    if (HAS_PQ) wv *= pq[b * 1024 + d];
    waT[h][d] = wv;
  }
  __syncthreads();
  const int w = threadIdx.x >> 6, l = threadIdx.x & 63;
  for (int g = blockIdx.x * 4 + w; g < 1024; g += gridDim.x * 4) {
    const size_t r0 = (size_t)b * 4096 + g * 4;
    float cur[64];  // idx = rr*16 + h
#pragma unroll
    for (int i = 0; i < 64; ++i) cur[i] = 0.f;
    for (int i = 0; i < 8; ++i) {
      const int d = i * 128 + l * 2;
      float xv[4][2];
#pragma unroll
      for (int rr = 0; rr < 4; ++rr) {
        ushort2 xq = *reinterpret_cast<const ushort2*>(&X[(r0 + rr) * 1024 + d]);
        xv[rr][0] = bf2f(xq.x); xv[rr][1] = bf2f(xq.y);
      }
#pragma unroll
      for (int h = 0; h < 16; ++h) {
        float2 wv = *reinterpret_cast<const float2*>(&waT[h][d]);
#pragma unroll
        for (int rr = 0; rr < 4; ++rr)
          cur[rr * 16 + h] += xv[rr][0] * wv.x + xv[rr][1] * wv.y;
      }
    }
#pragma unroll
    for (int s = 0; s < 6; ++s) {
      const int m = 1 << s;
      const int bit = (l >> s) & 1;
#pragma unroll
      for (int j = 0; j < (32 >> s); ++j) {
        const float mine = bit ? cur[2 * j + 1] : cur[2 * j];
        const float other = bit ? cur[2 * j] : cur[2 * j + 1];
        cur[j] = mine + __shfl_xor(other, m, 64);
      }
    }
    const int rr = l >> 4, h = l & 15;
    const int si = g * 4 + rr;
    score[((size_t)b * 16 + h) * 4096 + si] =
        (cur[0] + bias[h]) * scale + mask[b * 4096 + si];
  }
}

// --- softmax over S (in place), one block per (b,h) row --------------------
__global__ __launch_bounds__(256) void k_softmax(float* __restrict__ sc) {
  __shared__ float red[8];
  float* p = sc + (size_t)blockIdx.x * 4096;
  const int t = threadIdx.x, w = t >> 6, l = t & 63;
  float v[16];
  float mx = -3.0e38f;
#pragma unroll
  for (int i = 0; i < 16; ++i) { v[i] = p[t + i * 256]; mx = fmaxf(mx, v[i]); }
#pragma unroll
  for (int m = 1; m < 64; m <<= 1) mx = fmaxf(mx, __shfl_xor(mx, m, 64));
  if (l == 0) red[w] = mx;
  __syncthreads();
  mx = fmaxf(fmaxf(red[0], red[1]), fmaxf(red[2], red[3]));
  float sum = 0.f;
#pragma unroll
  for (int i = 0; i < 16; ++i) { v[i] = __expf(v[i] - mx); sum += v[i]; }
#pragma unroll
  for (int m = 1; m < 64; m <<= 1) sum += __shfl_xor(sum, m, 64);
  if (l == 0) red[4 + w] = sum;
  __syncthreads();
  const float inv = 1.f / (red[4] + red[5] + red[6] + red[7]);
#pragma unroll
  for (int i = 0; i < 16; ++i) p[t + i * 256] = v[i] * inv;
}

// --- pooled[b,d] = sum_s w[b, d>>6, s] * X[b,s,d]  (bf16 X, atomics) -------
__global__ __launch_bounds__(256) void k_pool(const float* __restrict__ wgt,
                                              const u16* __restrict__ X,
                                              float* __restrict__ pooled) {
  __shared__ float wl[16][132];
  const int b = blockIdx.x >> 5, c = blockIdx.x & 31;
  const int s0 = c * 128;
  for (int t = threadIdx.x; t < 2048; t += 256) {
    const int h = t >> 7, si = t & 127;
    wl[h][si] = wgt[((size_t)b * 16 + h) * 4096 + s0 + si];
  }
  __syncthreads();
  const int d0 = threadIdx.x * 4, h = threadIdx.x >> 4;
  float a0 = 0, a1 = 0, a2 = 0, a3 = 0;
  for (int si = 0; si < 128; ++si) {
    const float wv = wl[h][si];
    const size_t base = ((size_t)b * 4096 + s0 + si) * 1024 + d0;
    ushort4 xq = *reinterpret_cast<const ushort4*>(X + base);
    a0 += wv * bf2f(xq.x); a1 += wv * bf2f(xq.y);
    a2 += wv * bf2f(xq.z); a3 += wv * bf2f(xq.w);
  }
  atomicAdd(&pooled[b * 1024 + d0 + 0], a0);
  atomicAdd(&pooled[b * 1024 + d0 + 1], a1);
  atomicAdd(&pooled[b * 1024 + d0 + 2], a2);
  atomicAdd(&pooled[b * 1024 + d0 + 3], a3);
}

// ---------------------------------------------------------------------------
extern "C" void kernel_launch(void* const* d_in, const int* in_sizes, int n_in,
                              void* d_out, int out_size, void* d_ws, size_t ws_size,
                              hipStream_t stream) {
  (void)in_sizes; (void)n_in; (void)out_size; (void)ws_size;
  const float* x    = (const float*)d_in[0];
  const float* mask = (const float*)d_in[1];
  const float* Wq   = (const float*)d_in[2];
  const float* bq   = (const float*)d_in[3];
  const float* Wqa  = (const float*)d_in[4];
  const float* bqa  = (const float*)d_in[5];
  const float* Wk   = (const float*)d_in[6];
  const float* bk   = (const float*)d_in[7];
  const float* Wka  = (const float*)d_in[8];
  const float* bka  = (const float*)d_in[9];
  const float* Wt   = (const float*)d_in[10];
  const float* bt   = (const float*)d_in[11];
  float* out = (float*)d_out;
  char* ws = (char*)d_ws;

  size_t off = 0;
  auto take = [&](size_t b) { char* p = ws + off; off += (b + 255) & ~(size_t)255; return p; };
  u16*   xb    = (u16*)  take(67108864);   // x bf16
  u16*   qb    = (u16*)  take(67108864);   // q bf16
  u16*   kb    = (u16*)  take(67108864);   // k bf16
  u16*   Wqkt  = (u16*)  take(4194304);    // [Wq^T ; Wk^T] (2048 x 1024) bf16
  u16*   Wtt   = (u16*)  take(2097152);    // Wt^T bf16
  u16*   Wbt   = (u16*)  take(16777216);   // per-batch out weights (8x1024x1024)
  float* sc    = (float*)take(2097152);    // (B,H,S) scores
  float* pq    = (float*)take(32768);      // pooled_q (B,1024)
  float* pk    = (float*)take(32768);      // raw pooled_k (B,1024)

  // prep
  k_cvt<<<2048, 256, 0, stream>>>(x, xb, 8388608);
  k_transw<<<dim3(32, 32), 256, 0, stream>>>(Wq, Wqkt);
  k_transw<<<dim3(32, 32), 256, 0, stream>>>(Wk, Wqkt + 1024 * 1024);
  k_transw<<<dim3(32, 32), 256, 0, stream>>>(Wt, Wtt);

  // fused q,k = x @ [Wq|Wk] + [bq|bk]   (128 row-tiles x 8 col-tiles)
  k_gemm8<0><<<1024, 512, 0, stream>>>(xb, Wqkt, bq, bk, nullptr, nullptr, qb, kb, 8);

  // q path
  k_score<0><<<dim3(128, 8), 256, 0, stream>>>(qb, Wqa, bqa, mask, nullptr, sc, 0.125f);
  k_softmax<<<128, 256, 0, stream>>>(sc);
  hipMemsetAsync(pq, 0, 32768, stream);
  k_pool<<<256, 256, 0, stream>>>(sc, qb, pq);

  // k path (mixed_qk factored out)
  k_score<1><<<dim3(128, 8), 256, 0, stream>>>(kb, Wka, bka, mask, pq, sc, 0.125f);
  k_softmax<<<128, 256, 0, stream>>>(sc);
  hipMemsetAsync(pk, 0, 32768, stream);
  k_pool<<<256, 256, 0, stream>>>(sc, kb, pk);

  // out = (q .* pk .* pq) @ Wt + bt + q  ==  q @ W_b + bt + q
  k_wbt<<<4096, 256, 0, stream>>>(Wtt, pk, pq, Wbt);
  k_gemm8<2><<<512, 512, 0, stream>>>(qb, Wbt, bt, nullptr, qb, out, nullptr, nullptr, 4);
}